// Round 6
// baseline (7698.026 us; speedup 1.0000x reference)
//
#include <hip/hip_runtime.h>
#include <math.h>

#define H        1024
#define TSTEPS   2048
#define NWG      64
#define NT       1024
#define PAD      68            // padded segment stride (floats)
#define SENT     0xFFFFFFFFu   // -NaN bit pattern: h can never be this

typedef unsigned u32x4 __attribute__((ext_vector_type(4)));

// 16B AGENT-scope load (sc1 only — matches compiler's relaxed-agent atomic;
// sc0+sc1 = system scope, measured 1.55x slower in R4).
__device__ __forceinline__ u32x4 load16_agent(const unsigned* p) {
    u32x4 r;
    asm volatile("global_load_dwordx4 %0, %1, off sc1\n\ts_waitcnt vmcnt(0)"
                 : "=v"(r) : "v"(p) : "memory");
    return r;
}

__device__ __forceinline__ float fsig(float x)   { return 1.0f / (1.0f + __expf(-x)); }
__device__ __forceinline__ float ftanh_(float x) { return 1.0f - 2.0f / (__expf(2.0f * x) + 1.0f); }

__global__ __launch_bounds__(NT, 1) void lstm_persistent(
    const float* __restrict__ z,   const float* __restrict__ Wih,
    const float* __restrict__ Whh, const float* __restrict__ b_ih,
    const float* __restrict__ b_hh,
    const float* __restrict__ W1,  const float* __restrict__ b1,
    const float* __restrict__ W2,  const float* __restrict__ b2,
    const float* __restrict__ W3,  const float* __restrict__ b3,
    float* __restrict__ out, float* __restrict__ hs)
{
    __shared__ __align__(16) float hbuf[2][16 * PAD];   // double-buffered h row
    __shared__ __align__(16) float mlp_buf[4][16 * PAD];
    __shared__ float a1_lds[4][32];
    __shared__ float a2_lds[4][32];

    const int tid  = threadIdx.x;
    const int wg   = blockIdx.x;
    const int wave = tid >> 6;       // wave w owns element E = wg*16 + w
    const int lane = tid & 63;
    const int g    = lane >> 4;      // gate 0=i,1=f,2=g,3=o
    const int seg  = lane & 15;      // 64-col segment
    const int E    = wg * 16 + wave;
    const int grow = g * H + E;
    const float bias = b_ih[grow] + b_hh[grow];

    // ---- stage z -> hbuf[0] ----
    if (tid < 256) {
        float4 zv = *(const float4*)(z + tid * 4);
        *(float4*)(&hbuf[0][(tid >> 4) * PAD + (tid & 15) * 4]) = zv;
    }
    __syncthreads();

    // ---- weights (Wc = Wih+Whh) into regs; fused step-0 dot (x=z, h=c=0) ----
    float4 wreg[16];
    float s0 = 0.f, s1 = 0.f, s2 = 0.f, s3 = 0.f;
    const float* wihp = Wih + (size_t)grow * H + seg * 64;
    const float* whhp = Whh + (size_t)grow * H + seg * 64;
#pragma unroll
    for (int k = 0; k < 16; ++k) {
        float4 a  = *(const float4*)(wihp + 4 * k);
        float4 b  = *(const float4*)(whhp + 4 * k);
        float4 zz = *(const float4*)(&hbuf[0][seg * PAD + 4 * k]);
        float d = a.x * zz.x + a.y * zz.y + a.z * zz.z + a.w * zz.w;
        if ((k & 3) == 0) s0 += d; else if ((k & 3) == 1) s1 += d;
        else if ((k & 3) == 2) s2 += d; else s3 += d;
        wreg[k] = make_float4(a.x + b.x, a.y + b.y, a.z + b.z, a.w + b.w);
    }
    float c_reg;
    {
        float acc = (s0 + s1) + (s2 + s3);
        acc += __shfl_xor(acc, 1); acc += __shfl_xor(acc, 2);
        acc += __shfl_xor(acc, 4); acc += __shfl_xor(acc, 8);
        acc += bias;
        float sigv = fsig(acc), tanv = ftanh_(acc);   // parallel nonlinearities
        float si = __shfl(sigv, 0), tg = __shfl(tanv, 32), so = __shfl(sigv, 48);
        c_reg = si * tg;                               // c_prev = 0
        float h = so * ftanh_(c_reg);
        if (lane == 0)
            __hip_atomic_store((unsigned*)hs + E, __float_as_uint(h),
                               __ATOMIC_RELAXED, __HIP_MEMORY_SCOPE_AGENT);
    }

    // ---- main recurrence: ONE barrier per step, all-in-wave combine ----
    for (int t = 1; t < TSTEPS; ++t) {
        if (tid < 256) {   // pollers: waves 0..3, 16B each, agent scope
            const unsigned* p = (const unsigned*)hs + (size_t)(t - 1) * H + tid * 4;
            u32x4 v;
            for (;;) {
                v = load16_agent(p);
                if (v.x != SENT && v.y != SENT && v.z != SENT && v.w != SENT) break;
            }
            float* dst = &hbuf[t & 1][(tid >> 4) * PAD + (tid & 15) * 4];
            dst[0] = __uint_as_float(v.x); dst[1] = __uint_as_float(v.y);
            dst[2] = __uint_as_float(v.z); dst[3] = __uint_as_float(v.w);
        }
        __syncthreads();                           // B1: row t-1 staged

        const float* hb = &hbuf[t & 1][seg * PAD];
        float q0 = 0.f, q1 = 0.f, q2 = 0.f, q3 = 0.f;
#pragma unroll
        for (int k = 0; k < 16; ++k) {
            float4 h4 = *(const float4*)(hb + 4 * k);
            float4 wv = wreg[k];
            float d = wv.x * h4.x + wv.y * h4.y + wv.z * h4.z + wv.w * h4.w;
            if ((k & 3) == 0) q0 += d; else if ((k & 3) == 1) q1 += d;
            else if ((k & 3) == 2) q2 += d; else q3 += d;
        }
        float a2 = (q0 + q1) + (q2 + q3);
        a2 += __shfl_xor(a2, 1); a2 += __shfl_xor(a2, 2);
        a2 += __shfl_xor(a2, 4); a2 += __shfl_xor(a2, 8);
        a2 += bias;
        float sigv = fsig(a2), tanv = ftanh_(a2);  // i,f,o sig + g tanh in parallel
        float si = __shfl(sigv, 0),  sf = __shfl(sigv, 16);
        float tg = __shfl(tanv, 32), so = __shfl(sigv, 48);
        float cn = sf * c_reg + si * tg;
        float hn = so * ftanh_(cn);
        c_reg = cn;
        if (lane == 0)
            __hip_atomic_store((unsigned*)(hs + (size_t)t * H) + E,
                               __float_as_uint(hn),
                               __ATOMIC_RELAXED, __HIP_MEMORY_SCOPE_AGENT);
    }

    // ---- MLP tail: 4 groups x 256 threads, each group one row at a time ----
    const int local = tid & 255;
    const int grp   = tid >> 8;      // 0..3
    const int row32 = local >> 3;    // 0..31
    const int sub   = local & 7;     // 0..7
    for (int ti = 0; ti < 8; ++ti) {
        int t = wg * 32 + ti * 4 + grp;
        __syncthreads();                           // WAR: prior mlp_buf/a_lds use
        {
            const unsigned* p = (const unsigned*)hs + (size_t)t * H + local * 4;
            u32x4 v;
            for (;;) {
                v = load16_agent(p);
                if (v.x != SENT && v.y != SENT && v.z != SENT && v.w != SENT) break;
            }
            float* dst = &mlp_buf[grp][(local >> 4) * PAD + (local & 15) * 4];
            dst[0] = __uint_as_float(v.x); dst[1] = __uint_as_float(v.y);
            dst[2] = __uint_as_float(v.z); dst[3] = __uint_as_float(v.w);
        }
        __syncthreads();                           // row staged

        float acc1 = 0.f;
        const float* w1p = W1 + (size_t)row32 * H + sub * 128;
#pragma unroll
        for (int k = 0; k < 32; ++k) {
            float4 wv = *(const float4*)(w1p + 4 * k);
            int c = sub * 128 + 4 * k;
            float4 h4 = *(const float4*)(&mlp_buf[grp][(c >> 6) * PAD + (c & 63)]);
            acc1 += wv.x * h4.x + wv.y * h4.y + wv.z * h4.z + wv.w * h4.w;
        }
        acc1 += __shfl_xor(acc1, 1); acc1 += __shfl_xor(acc1, 2); acc1 += __shfl_xor(acc1, 4);
        if (sub == 0) a1_lds[grp][row32] = fmaxf(acc1 + b1[row32], 0.f);
        __syncthreads();                           // a1 ready

        if (local < 32) {
            float a = 0.f;
#pragma unroll
            for (int k = 0; k < 32; ++k) a += W2[local * 32 + k] * a1_lds[grp][k];
            a2_lds[grp][local] = fmaxf(a + b2[local], 0.f);
        }
        __syncthreads();                           // a2 ready

        if (local < 64) {
            float a = 0.f;
#pragma unroll
            for (int k = 0; k < 32; ++k) a += W3[local * 32 + k] * a2_lds[grp][k];
            out[(size_t)t * 64 + local] = a + b3[local];
        }
    }
}

extern "C" void kernel_launch(void* const* d_in, const int* in_sizes, int n_in,
                              void* d_out, int out_size, void* d_ws, size_t ws_size,
                              hipStream_t stream) {
    const float* z    = (const float*)d_in[0];
    const float* Wih  = (const float*)d_in[1];
    const float* Whh  = (const float*)d_in[2];
    const float* b_ih = (const float*)d_in[3];
    const float* b_hh = (const float*)d_in[4];
    const float* W1   = (const float*)d_in[5];
    const float* b1   = (const float*)d_in[6];
    const float* W2   = (const float*)d_in[7];
    const float* b2   = (const float*)d_in[8];
    const float* W3   = (const float*)d_in[9];
    const float* b3   = (const float*)d_in[10];
    float* out = (float*)d_out;

    float* hs = (float*)d_ws;   // TSTEPS*H floats = 8 MB, contiguous rows

    // Sentinel-fill hs: 0xFF bytes -> -NaN, unreachable as h.
    hipMemsetAsync(hs, 0xFF, (size_t)TSTEPS * H * sizeof(float), stream);
    hipLaunchKernelGGL(lstm_persistent, dim3(NWG), dim3(NT), 0, stream,
                       z, Wih, Whh, b_ih, b_hh, W1, b1, W2, b2, W3, b3,
                       out, hs);
}

// Round 7
// 5202.692 us; speedup vs baseline: 1.4796x; 1.4796x over previous
//
#include <hip/hip_runtime.h>
#include <math.h>

#define H        1024
#define TSTEPS   2048
#define NWG      64
#define NT       1024
#define CH       20            // dwords per 16-float chunk (16 data + 4 pad): uniform banks
#define PAD      68            // MLP staging stride (R5-proven)
#define SENT     0xFFFFFFFFu   // -NaN bit pattern: h can never be this

typedef unsigned u32x4 __attribute__((ext_vector_type(4)));

// 16B AGENT-scope load (sc1 only — matches compiler's relaxed-agent atomic;
// sc0+sc1 = system scope, measured 1.55x slower in R4).
__device__ __forceinline__ u32x4 load16_agent(const unsigned* p) {
    u32x4 r;
    asm volatile("global_load_dwordx4 %0, %1, off sc1\n\ts_waitcnt vmcnt(0)"
                 : "=v"(r) : "v"(p) : "memory");
    return r;
}

__device__ __forceinline__ float fsig(float x)   { return 1.0f / (1.0f + __expf(-x)); }
__device__ __forceinline__ float ftanh_(float x) { return 1.0f - 2.0f / (__expf(2.0f * x) + 1.0f); }

__global__ __launch_bounds__(NT, 1) void lstm_persistent(
    const float* __restrict__ z,   const float* __restrict__ Wih,
    const float* __restrict__ Whh, const float* __restrict__ b_ih,
    const float* __restrict__ b_hh,
    const float* __restrict__ W1,  const float* __restrict__ b1,
    const float* __restrict__ W2,  const float* __restrict__ b2,
    const float* __restrict__ W3,  const float* __restrict__ b3,
    float* __restrict__ out, float* __restrict__ hs)
{
    __shared__ __align__(16) float hbuf[2][64 * CH];   // double-buffered input row
    __shared__ volatile unsigned h_out[2][16];         // per-wave h handoff
    __shared__ __align__(16) float mlp_buf[4][16 * PAD];
    __shared__ float a1_lds[4][32];
    __shared__ float a2_lds[4][32];

    const int tid  = threadIdx.x;
    const int wg   = blockIdx.x;
    const int wave = tid >> 6;       // wave w owns element E = wg*16 + w entirely
    const int lane = tid & 63;
    const int E    = wg * 16 + wave;

    if (tid < 32) h_out[tid >> 4][tid & 15] = SENT;

    // ---- stage z -> hbuf[0] (chunk layout: chunk c at dword c*CH) ----
    if (tid < 256) {
        float4 zv = *(const float4*)(z + tid * 4);
        *(float4*)(&hbuf[0][(tid >> 2) * CH + (tid & 3) * 4]) = zv;
    }
    __syncthreads();

    // ---- weights: lane holds cols [16*lane,16*lane+16) of all 4 gates of E;
    //      fused step-0 dot (x=z, h=c=0) ----
    float4 wreg[4][4];
    float  bias[4];
    float  acc[4];
#pragma unroll
    for (int g = 0; g < 4; ++g) {
        const size_t row = (size_t)(g * H + E);
        const float* ap = Wih + row * H + lane * 16;
        const float* bp = Whh + row * H + lane * 16;
        bias[g] = b_ih[row] + b_hh[row];
        acc[g] = 0.f;
#pragma unroll
        for (int k = 0; k < 4; ++k) {
            float4 a  = *(const float4*)(ap + 4 * k);
            float4 b  = *(const float4*)(bp + 4 * k);
            float4 zz = *(const float4*)(&hbuf[0][lane * CH + 4 * k]);
            acc[g] += a.x * zz.x + a.y * zz.y + a.z * zz.z + a.w * zz.w;
            wreg[g][k] = make_float4(a.x + b.x, a.y + b.y, a.z + b.z, a.w + b.w);
        }
    }
#pragma unroll
    for (int m = 1; m < 64; m <<= 1) {
#pragma unroll
        for (int g = 0; g < 4; ++g) acc[g] += __shfl_xor(acc[g], m);
    }
    float c_reg;
    {
        float gi = acc[0] + bias[0], gg = acc[2] + bias[2], go = acc[3] + bias[3];
        c_reg = fsig(gi) * ftanh_(gg);                 // c_prev = 0
        float hn = fsig(go) * ftanh_(c_reg);
        if (lane == 0) h_out[0][wave] = __float_as_uint(hn);
        if (wave == 15) {                              // gather + coalesced 64B store
            unsigned v;
            do { v = h_out[0][lane & 15]; } while (!__all(v != SENT));
            if (lane < 16) {
                __hip_atomic_store((unsigned*)hs + wg * 16 + lane, v,
                                   __ATOMIC_RELAXED, __HIP_MEMORY_SCOPE_AGENT);
                h_out[0][lane] = SENT;                 // reset for step 2
                hbuf[1][wg * CH + lane] = __uint_as_float(v);  // self-copy (skip own poll)
            }
        }
    }

    // ---- main recurrence: ONE barrier/step ----
    for (int t = 1; t < TSTEPS; ++t) {
        const int par = t & 1;                         // input buffer for row t-1
        if (tid < 256 && (tid >> 2) != wg) {           // pollers skip own chunk
            const unsigned* p = (const unsigned*)hs + (size_t)(t - 1) * H + tid * 4;
            u32x4 v;
            for (;;) {
                v = load16_agent(p);
                if (v.x != SENT && v.y != SENT && v.z != SENT && v.w != SENT) break;
            }
            float* dst = &hbuf[par][(tid >> 2) * CH + (tid & 3) * 4];
            dst[0] = __uint_as_float(v.x); dst[1] = __uint_as_float(v.y);
            dst[2] = __uint_as_float(v.z); dst[3] = __uint_as_float(v.w);
        }
        __syncthreads();                               // B1: row t-1 staged

        float a4[4] = {0.f, 0.f, 0.f, 0.f};
        const float* hb = &hbuf[par][lane * CH];
#pragma unroll
        for (int k = 0; k < 4; ++k) {
            float4 h4 = *(const float4*)(hb + 4 * k);
#pragma unroll
            for (int g = 0; g < 4; ++g) {
                float4 wv = wreg[g][k];
                a4[g] += wv.x * h4.x + wv.y * h4.y + wv.z * h4.z + wv.w * h4.w;
            }
        }
#pragma unroll
        for (int m = 1; m < 64; m <<= 1) {
#pragma unroll
            for (int g = 0; g < 4; ++g) a4[g] += __shfl_xor(a4[g], m);
        }
        float gi = a4[0] + bias[0], gf = a4[1] + bias[1];
        float gg = a4[2] + bias[2], go = a4[3] + bias[3];
        float cn = fsig(gf) * c_reg + fsig(gi) * ftanh_(gg);
        float hn = fsig(go) * ftanh_(cn);
        c_reg = cn;
        if (lane == 0) h_out[par][wave] = __float_as_uint(hn);
        if (wave == 15) {
            unsigned v;
            do { v = h_out[par][lane & 15]; } while (!__all(v != SENT));
            if (lane < 16) {
                __hip_atomic_store((unsigned*)(hs + (size_t)t * H) + wg * 16 + lane, v,
                                   __ATOMIC_RELAXED, __HIP_MEMORY_SCOPE_AGENT);
                h_out[par][lane] = SENT;               // reset for t+2
                hbuf[par ^ 1][wg * CH + lane] = __uint_as_float(v);  // self-copy
            }
        }
    }

    // ---- MLP tail: 4 groups x 256 threads (R5-proven, unchanged) ----
    const int local = tid & 255;
    const int grp   = tid >> 8;      // 0..3
    const int row32 = local >> 3;    // 0..31
    const int sub   = local & 7;     // 0..7
    for (int ti = 0; ti < 8; ++ti) {
        int t = wg * 32 + ti * 4 + grp;
        __syncthreads();                               // WAR: prior mlp_buf/a_lds use
        {
            const unsigned* p = (const unsigned*)hs + (size_t)t * H + local * 4;
            u32x4 v;
            for (;;) {
                v = load16_agent(p);
                if (v.x != SENT && v.y != SENT && v.z != SENT && v.w != SENT) break;
            }
            float* dst = &mlp_buf[grp][(local >> 4) * PAD + (local & 15) * 4];
            dst[0] = __uint_as_float(v.x); dst[1] = __uint_as_float(v.y);
            dst[2] = __uint_as_float(v.z); dst[3] = __uint_as_float(v.w);
        }
        __syncthreads();                               // row staged

        float acc1 = 0.f;
        const float* w1p = W1 + (size_t)row32 * H + sub * 128;
#pragma unroll
        for (int k = 0; k < 32; ++k) {
            float4 wv = *(const float4*)(w1p + 4 * k);
            int c = sub * 128 + 4 * k;
            float4 h4 = *(const float4*)(&mlp_buf[grp][(c >> 6) * PAD + (c & 63)]);
            acc1 += wv.x * h4.x + wv.y * h4.y + wv.z * h4.z + wv.w * h4.w;
        }
        acc1 += __shfl_xor(acc1, 1); acc1 += __shfl_xor(acc1, 2); acc1 += __shfl_xor(acc1, 4);
        if (sub == 0) a1_lds[grp][row32] = fmaxf(acc1 + b1[row32], 0.f);
        __syncthreads();                               // a1 ready

        if (local < 32) {
            float a = 0.f;
#pragma unroll
            for (int k = 0; k < 32; ++k) a += W2[local * 32 + k] * a1_lds[grp][k];
            a2_lds[grp][local] = fmaxf(a + b2[local], 0.f);
        }
        __syncthreads();                               // a2 ready

        if (local < 64) {
            float a = 0.f;
#pragma unroll
            for (int k = 0; k < 32; ++k) a += W3[local * 32 + k] * a2_lds[grp][k];
            out[(size_t)t * 64 + local] = a + b3[local];
        }
    }
}

extern "C" void kernel_launch(void* const* d_in, const int* in_sizes, int n_in,
                              void* d_out, int out_size, void* d_ws, size_t ws_size,
                              hipStream_t stream) {
    const float* z    = (const float*)d_in[0];
    const float* Wih  = (const float*)d_in[1];
    const float* Whh  = (const float*)d_in[2];
    const float* b_ih = (const float*)d_in[3];
    const float* b_hh = (const float*)d_in[4];
    const float* W1   = (const float*)d_in[5];
    const float* b1   = (const float*)d_in[6];
    const float* W2   = (const float*)d_in[7];
    const float* b2   = (const float*)d_in[8];
    const float* W3   = (const float*)d_in[9];
    const float* b3   = (const float*)d_in[10];
    float* out = (float*)d_out;

    float* hs = (float*)d_ws;   // TSTEPS*H floats = 8 MB, contiguous rows

    // Sentinel-fill hs: 0xFF bytes -> -NaN, unreachable as h.
    hipMemsetAsync(hs, 0xFF, (size_t)TSTEPS * H * sizeof(float), stream);
    hipLaunchKernelGGL(lstm_persistent, dim3(NWG), dim3(NT), 0, stream,
                       z, Wih, Whh, b_ih, b_hh, W1, b1, W2, b2, W3, b3,
                       out, hs);
}

// Round 9
// 4245.369 us; speedup vs baseline: 1.8133x; 1.2255x over previous
//
#include <hip/hip_runtime.h>
#include <math.h>

#define H        1024
#define TSTEPS   2048
#define NWG      64
#define NT       1024
#define PAD      68            // padded segment stride (floats): 0-conflict (R5)
#define SENT     0xFFFFFFFFu   // -NaN bit pattern: h can never be this

typedef unsigned u32x4 __attribute__((ext_vector_type(4)));

// 16B AGENT-scope load (sc1), load + waitcnt in ONE asm block (no compiler
// copies can slip between issue and completion — R8's split version raced).
__device__ __forceinline__ u32x4 load16_agent(const unsigned* p) {
    u32x4 r;
    asm volatile("global_load_dwordx4 %0, %1, off sc1\n\ts_waitcnt vmcnt(0)"
                 : "=v"(r) : "v"(p) : "memory");
    return r;
}

__device__ __forceinline__ float fsig(float x)   { return 1.0f / (1.0f + __expf(-x)); }
__device__ __forceinline__ float ftanh_(float x) { return 1.0f - 2.0f / (__expf(2.0f * x) + 1.0f); }

__global__ __launch_bounds__(NT, 1) void lstm_persistent(
    const float* __restrict__ z,   const float* __restrict__ Wih,
    const float* __restrict__ Whh, const float* __restrict__ b_ih,
    const float* __restrict__ b_hh,
    const float* __restrict__ W1,  const float* __restrict__ b1,
    const float* __restrict__ W2,  const float* __restrict__ b2,
    const float* __restrict__ W3,  const float* __restrict__ b3,
    float* __restrict__ out, float* __restrict__ hs)
{
    __shared__ __align__(16) float hbuf[2][16 * PAD];   // double-buffered h row
    __shared__ unsigned h_out[2][16];                   // per-wave h handoff
    __shared__ __align__(16) float mlp_buf[4][16 * PAD];
    __shared__ float a1_lds[4][32];
    __shared__ float a2_lds[4][32];

    const int tid  = threadIdx.x;
    const int wg   = blockIdx.x;
    const int wave = tid >> 6;       // wave w owns element E = wg*16 + w
    const int lane = tid & 63;
    const int g    = lane >> 4;      // gate 0=i,1=f,2=g,3=o
    const int seg  = lane & 15;      // 64-col segment
    const int E    = wg * 16 + wave;
    const int grow = g * H + E;
    const float bias = b_ih[grow] + b_hh[grow];

    if (tid < 32) h_out[tid >> 4][tid & 15] = SENT;

    // ---- stage z -> hbuf[0] ----
    if (tid < 256) {
        float4 zv = *(const float4*)(z + tid * 4);
        *(float4*)(&hbuf[0][(tid >> 4) * PAD + (tid & 15) * 4]) = zv;
    }
    __syncthreads();

    // ---- weights (Wc = Wih+Whh) into regs; fused step-0 dot (x=z, h=c=0) ----
    float4 wreg[16];
    float s0 = 0.f, s1 = 0.f, s2 = 0.f, s3 = 0.f;
    const float* wihp = Wih + (size_t)grow * H + seg * 64;
    const float* whhp = Whh + (size_t)grow * H + seg * 64;
#pragma unroll
    for (int k = 0; k < 16; ++k) {
        float4 a  = *(const float4*)(wihp + 4 * k);
        float4 b  = *(const float4*)(whhp + 4 * k);
        float4 zz = *(const float4*)(&hbuf[0][seg * PAD + 4 * k]);
        float d = a.x * zz.x + a.y * zz.y + a.z * zz.z + a.w * zz.w;
        if ((k & 3) == 0) s0 += d; else if ((k & 3) == 1) s1 += d;
        else if ((k & 3) == 2) s2 += d; else s3 += d;
        wreg[k] = make_float4(a.x + b.x, a.y + b.y, a.z + b.z, a.w + b.w);
    }
    float c_reg;   // replicated across all lanes of the wave (uniform)
    {
        float acc = (s0 + s1) + (s2 + s3);
        acc += __shfl_xor(acc, 1); acc += __shfl_xor(acc, 2);
        acc += __shfl_xor(acc, 4); acc += __shfl_xor(acc, 8);
        float val = acc + bias;
        float act = (g == 2) ? ftanh_(val) : fsig(val);   // parallel nonlinearity
        float si = __shfl(act, 0), tg = __shfl(act, 32), so = __shfl(act, 48);
        c_reg = si * tg;                                  // c_prev = 0
        float hn = so * ftanh_(c_reg);
        if (lane == 0) ((volatile unsigned*)h_out[0])[wave] = __float_as_uint(hn);
        if (wave == 15) {
            unsigned v;
            do { v = ((volatile unsigned*)h_out[0])[lane & 15]; } while (!__all(v != SENT));
            if (lane < 16) {
                __hip_atomic_store((unsigned*)hs + wg * 16 + lane, v,
                                   __ATOMIC_RELAXED, __HIP_MEMORY_SCOPE_AGENT);
                ((volatile unsigned*)h_out[0])[lane] = SENT;
                hbuf[1][(wg >> 2) * PAD + ((wg * 16) & 63) + lane] = __uint_as_float(v);
            }
        }
    }

    // ---- main recurrence: ONE barrier per step ----
    for (int t = 1; t < TSTEPS; ++t) {
        const int q = t & 1;
        if (tid < 256 && (tid >> 2) != wg) {   // pollers (waves 0-3), skip own chunk
            const unsigned* p = (const unsigned*)hs + (size_t)(t - 1) * H + tid * 4;
            u32x4 v;
            for (;;) {
                v = load16_agent(p);
                if (v.x != SENT && v.y != SENT && v.z != SENT && v.w != SENT) break;
            }
            float* dst = &hbuf[q][(tid >> 4) * PAD + (tid & 15) * 4];
            dst[0] = __uint_as_float(v.x); dst[1] = __uint_as_float(v.y);
            dst[2] = __uint_as_float(v.z); dst[3] = __uint_as_float(v.w);
        }
        __syncthreads();                       // B1: row t-1 staged

        const float* hb = &hbuf[q][seg * PAD];
        float q0 = 0.f, q1 = 0.f, q2 = 0.f, q3 = 0.f;
#pragma unroll
        for (int k = 0; k < 16; ++k) {
            float4 h4 = *(const float4*)(hb + 4 * k);
            float4 wv = wreg[k];
            float d = wv.x * h4.x + wv.y * h4.y + wv.z * h4.z + wv.w * h4.w;
            if ((k & 3) == 0) q0 += d; else if ((k & 3) == 1) q1 += d;
            else if ((k & 3) == 2) q2 += d; else q3 += d;
        }
        float a2 = (q0 + q1) + (q2 + q3);
        a2 += __shfl_xor(a2, 1); a2 += __shfl_xor(a2, 2);
        a2 += __shfl_xor(a2, 4); a2 += __shfl_xor(a2, 8);
        float val = a2 + bias;
        float act = (g == 2) ? ftanh_(val) : fsig(val);   // parallel nonlinearity
        float si = __shfl(act, 0),  sf = __shfl(act, 16);
        float tg = __shfl(act, 32), so = __shfl(act, 48);
        float cn = sf * c_reg + si * tg;                  // wave-uniform cell
        float hn = so * ftanh_(cn);
        c_reg = cn;
        if (lane == 0) ((volatile unsigned*)h_out[q])[wave] = __float_as_uint(hn);
        if (wave == 15) {                      // gather + coalesced 64B store
            unsigned v;
            do { v = ((volatile unsigned*)h_out[q])[lane & 15]; } while (!__all(v != SENT));
            if (lane < 16) {
                __hip_atomic_store((unsigned*)(hs + (size_t)t * H) + wg * 16 + lane, v,
                                   __ATOMIC_RELAXED, __HIP_MEMORY_SCOPE_AGENT);
                ((volatile unsigned*)h_out[q])[lane] = SENT;   // reset for t+2
                hbuf[q ^ 1][(wg >> 2) * PAD + ((wg * 16) & 63) + lane] =
                    __uint_as_float(v);        // self-copy: skip own poll at t+1
            }
        }
    }

    // ---- MLP tail: 4 groups x 256 threads (R5-proven) ----
    const int local = tid & 255;
    const int grp   = tid >> 8;      // 0..3
    const int row32 = local >> 3;    // 0..31
    const int sub   = local & 7;     // 0..7
    for (int ti = 0; ti < 8; ++ti) {
        int t = wg * 32 + ti * 4 + grp;
        __syncthreads();                       // WAR: prior mlp_buf/a_lds use
        {
            const unsigned* p = (const unsigned*)hs + (size_t)t * H + local * 4;
            u32x4 v;
            for (;;) {
                v = load16_agent(p);
                if (v.x != SENT && v.y != SENT && v.z != SENT && v.w != SENT) break;
            }
            float* dst = &mlp_buf[grp][(local >> 4) * PAD + (local & 15) * 4];
            dst[0] = __uint_as_float(v.x); dst[1] = __uint_as_float(v.y);
            dst[2] = __uint_as_float(v.z); dst[3] = __uint_as_float(v.w);
        }
        __syncthreads();                       // row staged

        float acc1 = 0.f;
        const float* w1p = W1 + (size_t)row32 * H + sub * 128;
#pragma unroll
        for (int k = 0; k < 32; ++k) {
            float4 wv = *(const float4*)(w1p + 4 * k);
            int c = sub * 128 + 4 * k;
            float4 h4 = *(const float4*)(&mlp_buf[grp][(c >> 6) * PAD + (c & 63)]);
            acc1 += wv.x * h4.x + wv.y * h4.y + wv.z * h4.z + wv.w * h4.w;
        }
        acc1 += __shfl_xor(acc1, 1); acc1 += __shfl_xor(acc1, 2); acc1 += __shfl_xor(acc1, 4);
        if (sub == 0) a1_lds[grp][row32] = fmaxf(acc1 + b1[row32], 0.f);
        __syncthreads();                       // a1 ready

        if (local < 32) {
            float a = 0.f;
#pragma unroll
            for (int k = 0; k < 32; ++k) a += W2[local * 32 + k] * a1_lds[grp][k];
            a2_lds[grp][local] = fmaxf(a + b2[local], 0.f);
        }
        __syncthreads();                       // a2 ready

        if (local < 64) {
            float a = 0.f;
#pragma unroll
            for (int k = 0; k < 32; ++k) a += W3[local * 32 + k] * a2_lds[grp][k];
            out[(size_t)t * 64 + local] = a + b3[local];
        }
    }
}

extern "C" void kernel_launch(void* const* d_in, const int* in_sizes, int n_in,
                              void* d_out, int out_size, void* d_ws, size_t ws_size,
                              hipStream_t stream) {
    const float* z    = (const float*)d_in[0];
    const float* Wih  = (const float*)d_in[1];
    const float* Whh  = (const float*)d_in[2];
    const float* b_ih = (const float*)d_in[3];
    const float* b_hh = (const float*)d_in[4];
    const float* W1   = (const float*)d_in[5];
    const float* b1   = (const float*)d_in[6];
    const float* W2   = (const float*)d_in[7];
    const float* b2   = (const float*)d_in[8];
    const float* W3   = (const float*)d_in[9];
    const float* b3   = (const float*)d_in[10];
    float* out = (float*)d_out;

    float* hs = (float*)d_ws;   // TSTEPS*H floats = 8 MB, contiguous rows

    // Sentinel-fill hs: 0xFF bytes -> -NaN, unreachable as h.
    hipMemsetAsync(hs, 0xFF, (size_t)TSTEPS * H * sizeof(float), stream);
    hipLaunchKernelGGL(lstm_persistent, dim3(NWG), dim3(NT), 0, stream,
                       z, Wih, Whh, b_ih, b_hh, W1, b1, W2, b2, W3, b3,
                       out, hs);
}